// Round 1
// baseline (22.390 us; speedup 1.0000x reference)
//
#include <hip/hip_runtime.h>

#define NCH 1024      // OUT_CH * IN_GROUP
#define HH 8
#define WW 8
#define CG 64         // channels per block (contiguous slice of C)
#define PB 128        // points per block
#define CSTRIDE 68    // padded LDS row stride in words (17*16B -> float4-aligned, spreads banks)

__global__ __launch_bounds__(256)
void spline_main(const float* __restrict__ xy,
                 const float* __restrict__ C,
                 const float* __restrict__ Tx,
                 const float* __restrict__ Ty,
                 float* __restrict__ out,
                 int npts, int ntx, int nty) {
    __shared__ float ctrl[HH * WW * CSTRIDE];   // [hw][ch], padded rows
    __shared__ float wts[PB][8];                // wx0,wx1,wx2, wy0,wy1,wy2, base_bits, pad

    const int bid   = blockIdx.x;
    const int cg    = bid & 15;     // 16 channel groups
    const int pg    = bid >> 4;
    const int cbase = cg * CG;
    const int pbase = pg * PB;
    const int t     = threadIdx.x;

    // ---- stage this block's 64 channels of C into LDS (transposed, padded) ----
    // C slice for channels [cbase, cbase+64) is contiguous: 4096 floats.
    const float* Cb = C + (size_t)cbase * (HH * WW);
    #pragma unroll
    for (int k = 0; k < (CG * HH * WW) / 256; ++k) {
        int idx = t + k * 256;
        int ch  = idx >> 6;         // local channel
        int hw  = idx & 63;         // h*8+w
        ctrl[hw * CSTRIDE + ch] = Cb[idx];
    }

    // ---- per-point de Boor weights (closed form for order 2) ----
    if (t < PB) {
        int n = pbase + t;
        float X = 0.f, Y = 0.f;
        if (n < npts) { X = xy[2 * n]; Y = xy[2 * n + 1]; }

        int kx = 0;
        for (int i = 0; i < ntx; ++i) if (Tx[i] <= X) kx = i;   // searchsorted(right)-1
        kx = min(max(kx, 2), ntx - 4);
        int ky = 0;
        for (int i = 0; i < nty; ++i) if (Ty[i] <= Y) ky = i;
        ky = min(max(ky, 2), nty - 4);

        float tkm1 = Tx[kx - 1], tk = Tx[kx], tk1 = Tx[kx + 1], tk2 = Tx[kx + 2];
        float d;
        d = tk1 - tkm1; float a10 = (X - tkm1) / (d == 0.f ? 1.f : d);
        d = tk2 - tk;   float a11 = (X - tk)   / (d == 0.f ? 1.f : d);
        d = tk1 - tk;   float a21 = (X - tk)   / (d == 0.f ? 1.f : d);
        float wx0 = (1.f - a21) * (1.f - a10);
        float wx1 = (1.f - a21) * a10 + a21 * (1.f - a11);
        float wx2 = a21 * a11;

        tkm1 = Ty[ky - 1]; tk = Ty[ky]; tk1 = Ty[ky + 1]; tk2 = Ty[ky + 2];
        d = tk1 - tkm1; float b10 = (Y - tkm1) / (d == 0.f ? 1.f : d);
        d = tk2 - tk;   float b11 = (Y - tk)   / (d == 0.f ? 1.f : d);
        d = tk1 - tk;   float b21 = (Y - tk)   / (d == 0.f ? 1.f : d);
        float wy0 = (1.f - b21) * (1.f - b10);
        float wy1 = (1.f - b21) * b10 + b21 * (1.f - b11);
        float wy2 = b21 * b11;

        int base = ((kx - 2) * WW + (ky - 2)) * CSTRIDE;   // LDS row offset of patch origin
        wts[t][0] = wx0; wts[t][1] = wx1; wts[t][2] = wx2;
        wts[t][3] = wy0; wts[t][4] = wy1; wts[t][5] = wy2;
        wts[t][6] = __int_as_float(base);
        wts[t][7] = 0.f;
    }
    __syncthreads();

    // ---- main loop: thread owns 4 consecutive channels, iterates 8 points ----
    const int ch_slot = t & 15;          // 16 channel slots * 4 ch
    const int p0      = t >> 4;          // 16 point slots
    const int choff   = ch_slot * 4;

    #pragma unroll
    for (int k = 0; k < PB / 16; ++k) {
        int p = p0 + k * 16;
        int n = pbase + p;

        float4 wa = *reinterpret_cast<const float4*>(&wts[p][0]); // wx0,wx1,wx2,wy0
        float4 wb = *reinterpret_cast<const float4*>(&wts[p][4]); // wy1,wy2,bits,pad
        int base  = __float_as_int(wb.z);

        const float wxv[3] = {wa.x, wa.y, wa.z};
        const float wyv[3] = {wa.w, wb.x, wb.y};
        const float* cp = &ctrl[base + choff];

        float4 acc = make_float4(0.f, 0.f, 0.f, 0.f);
        #pragma unroll
        for (int i = 0; i < 3; ++i) {
            float4 s = make_float4(0.f, 0.f, 0.f, 0.f);
            #pragma unroll
            for (int j = 0; j < 3; ++j) {
                const float4 cv = *reinterpret_cast<const float4*>(cp + (i * WW + j) * CSTRIDE);
                s.x = fmaf(wyv[j], cv.x, s.x);
                s.y = fmaf(wyv[j], cv.y, s.y);
                s.z = fmaf(wyv[j], cv.z, s.z);
                s.w = fmaf(wyv[j], cv.w, s.w);
            }
            acc.x = fmaf(wxv[i], s.x, acc.x);
            acc.y = fmaf(wxv[i], s.y, acc.y);
            acc.z = fmaf(wxv[i], s.z, acc.z);
            acc.w = fmaf(wxv[i], s.w, acc.w);
        }

        if (n < npts) {
            *reinterpret_cast<float4*>(&out[(size_t)n * NCH + cbase + choff]) = acc;
        }
    }
}

extern "C" void kernel_launch(void* const* d_in, const int* in_sizes, int n_in,
                              void* d_out, int out_size, void* d_ws, size_t ws_size,
                              hipStream_t stream) {
    const float* xy = (const float*)d_in[0];
    const float* C  = (const float*)d_in[1];
    const float* Tx = (const float*)d_in[2];
    const float* Ty = (const float*)d_in[3];
    float* out = (float*)d_out;

    int npts = in_sizes[0] / 2;
    int ntx  = in_sizes[2];
    int nty  = in_sizes[3];

    int pgs = (npts + PB - 1) / PB;
    dim3 grid(16 * pgs);
    dim3 block(256);
    hipLaunchKernelGGL(spline_main, grid, block, 0, stream,
                       xy, C, Tx, Ty, out, npts, ntx, nty);
}

// Round 2
// 21.735 us; speedup vs baseline: 1.0301x; 1.0301x over previous
//
#include <hip/hip_runtime.h>

#define NCH   1024     // OUT_CH * IN_GROUP
#define KHW   64       // H*W = GEMM K
#define BPT   256      // points per block  (M tile)
#define BCH   256      // channels per block (N tile)
#define AST   72       // A LDS row stride in bf16 elems (144 B: 16B-aligned, bank-staggered)

typedef __attribute__((ext_vector_type(8))) short  bf16x8;
typedef __attribute__((ext_vector_type(4))) float  f32x4;

__device__ __forceinline__ unsigned short f2bf(float f) {
    unsigned int u = __float_as_uint(f);
    u += 0x7FFFu + ((u >> 16) & 1u);          // round-to-nearest-even
    return (unsigned short)(u >> 16);
}

__global__ __launch_bounds__(512)
void spline_gemm(const float* __restrict__ xy,
                 const float* __restrict__ C,
                 const float* __restrict__ Tx,
                 const float* __restrict__ Ty,
                 float* __restrict__ out,
                 int npts, int ntx, int nty) {
    __shared__ unsigned short A[BPT * AST];   // W rows: 256 x 64 (padded to 72) bf16

    const int t     = threadIdx.x;
    const int cgrp  = blockIdx.x & 3;         // 4 channel groups of 256
    const int pgrp  = blockIdx.x >> 2;        // 64 point groups of 256
    const int pbase = pgrp * BPT;
    const int cbase = cgrp * BCH;

    // ---- zero A tile: 36864 B = 9216 dwords, 18 per thread ----
    int* A32 = (int*)A;
    #pragma unroll
    for (int k = 0; k < 18; ++k) A32[t + k * 512] = 0;
    __syncthreads();

    // ---- per-point quadratic B-spline weights, scattered 9-sparse into A ----
    if (t < BPT) {
        const int n = pbase + t;
        float X = 0.f, Y = 0.f;
        if (n < npts) { X = xy[2 * n]; Y = xy[2 * n + 1]; }

        int kx = 0; for (int i = 0; i < ntx; ++i) if (Tx[i] <= X) kx = i;
        kx = min(max(kx, 2), ntx - 4);
        int ky = 0; for (int i = 0; i < nty; ++i) if (Ty[i] <= Y) ky = i;
        ky = min(max(ky, 2), nty - 4);

        float tkm1 = Tx[kx - 1], tk = Tx[kx], tk1 = Tx[kx + 1], tk2 = Tx[kx + 2];
        float d;
        d = tk1 - tkm1; float a10 = (X - tkm1) / (d == 0.f ? 1.f : d);
        d = tk2 - tk;   float a11 = (X - tk)   / (d == 0.f ? 1.f : d);
        d = tk1 - tk;   float a21 = (X - tk)   / (d == 0.f ? 1.f : d);
        float wx0 = (1.f - a21) * (1.f - a10);
        float wx1 = (1.f - a21) * a10 + a21 * (1.f - a11);
        float wx2 = a21 * a11;

        tkm1 = Ty[ky - 1]; tk = Ty[ky]; tk1 = Ty[ky + 1]; tk2 = Ty[ky + 2];
        d = tk1 - tkm1; float b10 = (Y - tkm1) / (d == 0.f ? 1.f : d);
        d = tk2 - tk;   float b11 = (Y - tk)   / (d == 0.f ? 1.f : d);
        d = tk1 - tk;   float b21 = (Y - tk)   / (d == 0.f ? 1.f : d);
        float wy0 = (1.f - b21) * (1.f - b10);
        float wy1 = (1.f - b21) * b10 + b21 * (1.f - b11);
        float wy2 = b21 * b11;

        unsigned short* row = &A[t * AST + (kx - 2) * 8 + (ky - 2)];
        row[0]  = f2bf(wx0 * wy0); row[1]  = f2bf(wx0 * wy1); row[2]  = f2bf(wx0 * wy2);
        row[8]  = f2bf(wx1 * wy0); row[9]  = f2bf(wx1 * wy1); row[10] = f2bf(wx1 * wy2);
        row[16] = f2bf(wx2 * wy0); row[17] = f2bf(wx2 * wy1); row[18] = f2bf(wx2 * wy2);
    }
    __syncthreads();

    // ---- GEMM: 8 waves as 2 (point) x 4 (channel); wave tile 128 pts x 64 ch ----
    const int wid  = t >> 6;
    const int lane = t & 63;
    const int wm   = wid >> 2;        // 0..1
    const int wn   = wid & 3;         // 0..3
    const int l15  = lane & 15;
    const int l4   = lane >> 4;       // k-octet group

    f32x4 acc[8][4] = {};

    const float*          Cb = C + (size_t)(cbase + wn * 64 + l15) * KHW + l4 * 8;
    const unsigned short* Ab = A + (wm * 128 + l15) * AST + l4 * 8;

    #pragma unroll
    for (int kr = 0; kr < 2; ++kr) {
        bf16x8 a[8], b[4];
        #pragma unroll
        for (int mf = 0; mf < 8; ++mf)
            a[mf] = *(const bf16x8*)(Ab + mf * 16 * AST + kr * 32);
        #pragma unroll
        for (int nf = 0; nf < 4; ++nf) {
            const float* s = Cb + nf * 16 * KHW + kr * 32;
            f32x4 f0 = *(const f32x4*)s;
            f32x4 f1 = *(const f32x4*)(s + 4);
            bf16x8 bb;
            bb[0] = (short)f2bf(f0.x); bb[1] = (short)f2bf(f0.y);
            bb[2] = (short)f2bf(f0.z); bb[3] = (short)f2bf(f0.w);
            bb[4] = (short)f2bf(f1.x); bb[5] = (short)f2bf(f1.y);
            bb[6] = (short)f2bf(f1.z); bb[7] = (short)f2bf(f1.w);
            b[nf] = bb;
        }
        #pragma unroll
        for (int mf = 0; mf < 8; ++mf) {
            #pragma unroll
            for (int nf = 0; nf < 4; ++nf)
                acc[mf][nf] = __builtin_amdgcn_mfma_f32_16x16x32_bf16(
                                  a[mf], b[nf], acc[mf][nf], 0, 0, 0);
        }
    }

    // ---- epilogue: C/D layout col = lane&15, row = (lane>>4)*4 + reg ----
    #pragma unroll
    for (int mf = 0; mf < 8; ++mf) {
        const int row0 = pbase + wm * 128 + mf * 16 + l4 * 4;
        #pragma unroll
        for (int nf = 0; nf < 4; ++nf) {
            const size_t col = (size_t)cbase + wn * 64 + nf * 16 + l15;
            #pragma unroll
            for (int r = 0; r < 4; ++r) {
                const int row = row0 + r;
                if (row < npts)
                    out[(size_t)row * NCH + col] = acc[mf][nf][r];
            }
        }
    }
}

extern "C" void kernel_launch(void* const* d_in, const int* in_sizes, int n_in,
                              void* d_out, int out_size, void* d_ws, size_t ws_size,
                              hipStream_t stream) {
    const float* xy = (const float*)d_in[0];
    const float* C  = (const float*)d_in[1];
    const float* Tx = (const float*)d_in[2];
    const float* Ty = (const float*)d_in[3];
    float* out = (float*)d_out;

    int npts = in_sizes[0] / 2;
    int ntx  = in_sizes[2];
    int nty  = in_sizes[3];

    int pgs = (npts + BPT - 1) / BPT;
    dim3 grid(pgs * 4);
    dim3 block(512);
    hipLaunchKernelGGL(spline_gemm, grid, block, 0, stream,
                       xy, C, Tx, Ty, out, npts, ntx, nty);
}